// Round 8
// baseline (349.562 us; speedup 1.0000x reference)
//
#include <hip/hip_runtime.h>
#include <math.h>

typedef __attribute__((ext_vector_type(8))) short short8;
typedef __attribute__((ext_vector_type(4))) float floatx4;

__device__ __forceinline__ float sig(float z) { return 1.0f / (1.0f + __expf(-z)); }

__device__ __forceinline__ unsigned short f2bf(float f) {
    unsigned u = __float_as_uint(f);
    u = (u + 0x7FFFu + ((u >> 16) & 1u)) >> 16;
    return (unsigned short)u;
}

// pack two fp32 -> two RNE bf16 in one uint via v_perm
__device__ __forceinline__ unsigned int pack2bf(float a, float b) {
    unsigned ua = __float_as_uint(a), ub = __float_as_uint(b);
    ua += 0x7FFFu + ((ua >> 16) & 1u);
    ub += 0x7FFFu + ((ub >> 16) & 1u);
    return __builtin_amdgcn_perm(ub, ua, 0x07060302);
}

// All four W1 matrices -> bf16 pre-swizzled MFMA 16x16x32 B-frag order in one kernel.
// blk = (n>>4)*(H/32) + (k>>5), lane = ((k>>3)&3)*16 + (n&15), j = k&7.
__global__ void convert_all(const float* __restrict__ s0, const float* __restrict__ s1,
                            const float* __restrict__ s2, const float* __restrict__ s3,
                            unsigned short* __restrict__ ws) {
    int idx = blockIdx.x * 256 + threadIdx.x;          // 0 .. 458751
    const float* src; unsigned short* dst; int H, logH, local;
    if (idx < 262144) { src = s0; dst = ws; H = 512; logH = 9; local = idx; }
    else {
        int r = idx - 262144; int m = r >> 16; local = r & 65535;
        H = 256; logH = 8;
        src = (m == 0) ? s1 : (m == 1) ? s2 : s3;
        dst = ws + 262144 + m * 65536;
    }
    int n = local & (H - 1), k = local >> logH;
    int KT = H >> 5;
    int blk = (n >> 4) * KT + (k >> 5);
    int lane = ((k >> 3) & 3) * 16 + (n & 15);
    int j = k & 7;
    dst[(blk * 64 + lane) * 8 + j] = f2bf(src[local]);
}

struct PosS { float B0[512], B1[512], W2[1536], Q[4][8], Qd[4][8]; };
struct RpyS { float B0[256], B1[256], W2[512],  Q[8][8], Qd[8][8]; };

// Fused: 10240 blocks of 256 thr. f%5<2 -> pos tile (4 samples); f%5>=2 -> rpy head (8 samples).
// Per-wave acc = 64 AGPR (pos 2x8, rpy 4x4) + single-buffer B => ~<=168 regs -> 3 waves/SIMD.
// A tile 32 KB dyn (reused as fp32 reduce scratch after K loop) + ~10.5 KB statics -> 3 blocks/CU.
__global__ __launch_bounds__(256, 3)
void fused_mfma(const float* __restrict__ x,
                const float* __restrict__ pW0, const float* __restrict__ pb0,
                const float* __restrict__ pb1,
                const float* __restrict__ pW2, const float* __restrict__ pb2,
                const float* __restrict__ rW0_, const float* __restrict__ rb0_,
                const float* __restrict__ rb1_,
                const float* __restrict__ rW2_, const float* __restrict__ rb2_,
                const float* __restrict__ piW0, const float* __restrict__ pib0,
                const float* __restrict__ pib1,
                const float* __restrict__ piW2, const float* __restrict__ pib2,
                const float* __restrict__ yW0, const float* __restrict__ yb0,
                const float* __restrict__ yb1,
                const float* __restrict__ yW2, const float* __restrict__ yb2,
                const unsigned short* __restrict__ wsBase,
                float* __restrict__ out, int ns)
{
    extern __shared__ unsigned short sA[];      // 16384 shorts = 32 KB
    float* dynF = (float*)sA;                   // reuse after K loop
    __shared__ union { PosS p; RpyS r; } sU;

    const int tid = threadIdx.x;
    const int f = blockIdx.x;
    const int g = f / 5, r5 = f % 5;
    const size_t JTOT = (size_t)ns * 18, OUTA = (size_t)ns * 81, JANG = (size_t)ns * 87;
    const floatx4 z4 = {0.f, 0.f, 0.f, 0.f};
    const int w = tid >> 6, lane = tid & 63;
    const int quad = lane >> 4, col = lane & 15;
    const int srcl = lane & 47;

    if (r5 < 2) {
        // ============ POS: 7 -> 512 -> 512 -> 3, 4 samples (M=32) ============
        const int m0 = (g * 2 + r5) * 4;

        for (int i = tid; i < 512;  i += 256) { sU.p.B0[i] = pb0[i]; sU.p.B1[i] = pb1[i]; }
        for (int i = tid; i < 1536; i += 256) sU.p.W2[i] = pW2[i];
        if (tid < 56) {
            int m = tid / 14, c = tid % 14;
            float v = x[(m0 + m) * 14 + c];
            if (c < 7) sU.p.Q[m][c] = v; else sU.p.Qd[m][c - 7] = v;
        }
        __syncthreads();

        // build A: 512 items = (s in 0..3) x (gg in 0..127), 4 k per item
        const float4* W04 = (const float4*)pW0;
        #pragma unroll
        for (int t = 0; t < 2; ++t) {
            int item = tid + t * 256;
            int s = item >> 7, gg = item & 127;
            int kt = gg >> 3, kq = (gg >> 1) & 3, j0 = (gg & 1) * 4;
            int sw = kt & 7;
            int k = gg * 4;
            float q[7]; float4 w0r[7];
            #pragma unroll
            for (int i = 0; i < 7; i++) { q[i] = sU.p.Q[s][i]; w0r[i] = W04[i * 128 + gg]; }
            float hv[4], dv[4];
            #pragma unroll
            for (int jj = 0; jj < 4; jj++) {
                float z = sU.p.B0[k + jj];
                #pragma unroll
                for (int i = 0; i < 7; i++) z = fmaf(q[i], ((const float*)&w0r[i])[jj], z);
                float hh = sig(z);
                hv[jj] = hh; dv[jj] = hh - hh * hh;
            }
            const int rt = s >> 1, rb = (s & 1) * 8;
            {
                int cl = (kq * 16 + rb) ^ sw;
                uint2 v; v.x = pack2bf(hv[0], hv[1]); v.y = pack2bf(hv[2], hv[3]);
                *(uint2*)&sA[(rt * 16 + kt) * 512 + cl * 8 + j0] = v;
            }
            #pragma unroll
            for (int i = 0; i < 7; i++) {
                int cl = (kq * 16 + rb + 1 + i) ^ sw;
                uint2 v;
                v.x = pack2bf(dv[0] * ((const float*)&w0r[i])[0], dv[1] * ((const float*)&w0r[i])[1]);
                v.y = pack2bf(dv[2] * ((const float*)&w0r[i])[2], dv[3] * ((const float*)&w0r[i])[3]);
                *(uint2*)&sA[(rt * 16 + kt) * 512 + cl * 8 + j0] = v;
            }
        }
        __syncthreads();

        floatx4 acc[2][8];
        #pragma unroll
        for (int rt = 0; rt < 2; rt++)
            #pragma unroll
            for (int ct = 0; ct < 8; ct++) acc[rt][ct] = z4;

        const short8* bbase = (const short8*)wsBase + (size_t)(w * 128) * 64 + lane;
        #pragma unroll
        for (int kt = 0; kt < 16; ++kt) {
            const int sw = kt & 7;
            short8 bf[8];
            #pragma unroll
            for (int ct = 0; ct < 8; ++ct) bf[ct] = bbase[(ct * 16 + kt) * 64];
            short8 a0 = *(const short8*)&sA[(kt) * 512 + (lane ^ sw) * 8];
            short8 a1 = *(const short8*)&sA[(16 + kt) * 512 + (lane ^ sw) * 8];
            #pragma unroll
            for (int ct = 0; ct < 8; ++ct) {
                acc[0][ct] = __builtin_amdgcn_mfma_f32_16x16x32_bf16(a0, bf[ct], acc[0][ct], 0, 0, 0);
                acc[1][ct] = __builtin_amdgcn_mfma_f32_16x16x32_bf16(a1, bf[ct], acc[1][ct], 0, 0, 0);
            }
        }

        float ep[2][4][3];
        #pragma unroll
        for (int a = 0; a < 2; a++) for (int b = 0; b < 4; b++) for (int c = 0; c < 3; c++) ep[a][b][c] = 0.f;
        #pragma unroll
        for (int ct = 0; ct < 8; ++ct) {
            const int n = w * 128 + ct * 16 + col;
            const float b1n = sU.p.B1[n];
            const float w20 = sU.p.W2[n * 3], w21 = sU.p.W2[n * 3 + 1], w22 = sU.p.W2[n * 3 + 2];
            #pragma unroll
            for (int rt = 0; rt < 2; ++rt) {
                float z2c = __shfl(acc[rt][ct][0], srcl);
                float h2 = sig(z2c + b1n);
                float d2 = h2 - h2 * h2;
                #pragma unroll
                for (int r = 0; r < 4; ++r) {
                    float gg = ((quad & 1) == 0 && r == 0) ? h2 : d2 * acc[rt][ct][r];
                    ep[rt][r][0] = fmaf(gg, w20, ep[rt][r][0]);
                    ep[rt][r][1] = fmaf(gg, w21, ep[rt][r][1]);
                    ep[rt][r][2] = fmaf(gg, w22, ep[rt][r][2]);
                }
            }
        }
        #pragma unroll
        for (int mask = 1; mask <= 8; mask <<= 1)
            #pragma unroll
            for (int a = 0; a < 2; a++)
                #pragma unroll
                for (int b = 0; b < 4; b++)
                    #pragma unroll
                    for (int c = 0; c < 3; c++)
                        ep[a][b][c] += __shfl_xor(ep[a][b][c], mask);
        __syncthreads();                         // all waves done reading sA
        if (col == 0) {
            #pragma unroll
            for (int rt = 0; rt < 2; ++rt)
                #pragma unroll
                for (int r = 0; r < 4; ++r) {
                    int row = rt * 16 + quad * 4 + r;
                    dynF[(w * 32 + row) * 3 + 0] = ep[rt][r][0];
                    dynF[(w * 32 + row) * 3 + 1] = ep[rt][r][1];
                    dynF[(w * 32 + row) * 3 + 2] = ep[rt][r][2];
                }
        }
        __syncthreads();
        if (tid < 96) {
            int row = tid / 3, j = tid % 3;
            float v = dynF[row * 3 + j] + dynF[(32 + row) * 3 + j]
                    + dynF[(64 + row) * 3 + j] + dynF[(96 + row) * 3 + j];
            int i_row = row & 7, s = row >> 3;
            size_t M = m0 + s;
            if (i_row == 0) { v += pb2[j]; out[M * 18 + j] = v; out[OUTA + M * 6 + j] = v; }
            else            { out[JTOT + M * 63 + j * 7 + (i_row - 1)] = v;
                              out[JANG + M * 42 + j * 7 + (i_row - 1)] = v; }
            dynF[384 + row * 3 + j] = v;
        }
        __syncthreads();
        if (tid < 12) {
            int s = tid / 3, j = tid % 3;
            float vel = 0.f;
            #pragma unroll
            for (int i = 0; i < 7; i++)
                vel = fmaf(dynF[384 + (s * 8 + 1 + i) * 3 + j], sU.p.Qd[s][i], vel);
            out[(size_t)(m0 + s) * 18 + 9 + j] = vel;
        }
    } else {
        // ============ RPY: 7 -> 256 -> 256 -> 2, 8 samples (M=64) ============
        const int h = r5 - 2;
        const int m0 = g * 8;
        const float* W0 = (h == 0) ? rW0_ : (h == 1) ? piW0 : yW0;
        const float* b0 = (h == 0) ? rb0_ : (h == 1) ? pib0 : yb0;
        const float* b1 = (h == 0) ? rb1_ : (h == 1) ? pib1 : yb1;
        const float* W2 = (h == 0) ? rW2_ : (h == 1) ? piW2 : yW2;
        const float* b2 = (h == 0) ? rb2_ : (h == 1) ? pib2 : yb2;
        const unsigned short* wsW1 = wsBase + 262144 + h * 65536;

        if (tid < 256) { sU.r.B0[tid] = b0[tid]; sU.r.B1[tid] = b1[tid]; }
        for (int i = tid; i < 512; i += 256) sU.r.W2[i] = W2[i];
        if (tid < 112) {
            int m = tid / 14, c = tid % 14;
            float v = x[(m0 + m) * 14 + c];
            if (c < 7) sU.r.Q[m][c] = v; else sU.r.Qd[m][c - 7] = v;
        }
        __syncthreads();

        // build A: 512 items = (s in 0..7) x (gg in 0..63), 4 k per item
        const float4* W04 = (const float4*)W0;
        #pragma unroll
        for (int t = 0; t < 2; ++t) {
            int item = tid + t * 256;
            int s = item >> 6, gg = item & 63;
            int kt = gg >> 3, kq = (gg >> 1) & 3, j0 = (gg & 1) * 4;
            int sw = kt & 7;
            int k = gg * 4;
            float q[7]; float4 w0r[7];
            #pragma unroll
            for (int i = 0; i < 7; i++) { q[i] = sU.r.Q[s][i]; w0r[i] = W04[i * 64 + gg]; }
            float hv[4], dv[4];
            #pragma unroll
            for (int jj = 0; jj < 4; jj++) {
                float z = sU.r.B0[k + jj];
                #pragma unroll
                for (int i = 0; i < 7; i++) z = fmaf(q[i], ((const float*)&w0r[i])[jj], z);
                float hh = sig(z);
                hv[jj] = hh; dv[jj] = hh - hh * hh;
            }
            const int rt = s >> 1, rb = (s & 1) * 8;
            {
                int cl = (kq * 16 + rb) ^ sw;
                uint2 v; v.x = pack2bf(hv[0], hv[1]); v.y = pack2bf(hv[2], hv[3]);
                *(uint2*)&sA[(rt * 8 + kt) * 512 + cl * 8 + j0] = v;
            }
            #pragma unroll
            for (int i = 0; i < 7; i++) {
                int cl = (kq * 16 + rb + 1 + i) ^ sw;
                uint2 v;
                v.x = pack2bf(dv[0] * ((const float*)&w0r[i])[0], dv[1] * ((const float*)&w0r[i])[1]);
                v.y = pack2bf(dv[2] * ((const float*)&w0r[i])[2], dv[3] * ((const float*)&w0r[i])[3]);
                *(uint2*)&sA[(rt * 8 + kt) * 512 + cl * 8 + j0] = v;
            }
        }
        __syncthreads();

        floatx4 acc[4][4];
        #pragma unroll
        for (int rt = 0; rt < 4; rt++)
            #pragma unroll
            for (int ct = 0; ct < 4; ct++) acc[rt][ct] = z4;

        const short8* bbase = (const short8*)wsW1 + (size_t)(w * 32) * 64 + lane;
        #pragma unroll
        for (int kt = 0; kt < 8; ++kt) {
            const int sw = kt & 7;
            short8 bf[4];
            #pragma unroll
            for (int ct = 0; ct < 4; ++ct) bf[ct] = bbase[(ct * 8 + kt) * 64];
            short8 afr[4];
            #pragma unroll
            for (int rt = 0; rt < 4; ++rt)
                afr[rt] = *(const short8*)&sA[(rt * 8 + kt) * 512 + (lane ^ sw) * 8];
            #pragma unroll
            for (int ct = 0; ct < 4; ++ct)
                #pragma unroll
                for (int rt = 0; rt < 4; ++rt)
                    acc[rt][ct] = __builtin_amdgcn_mfma_f32_16x16x32_bf16(afr[rt], bf[ct], acc[rt][ct], 0, 0, 0);
        }

        float ep[4][4][2];
        #pragma unroll
        for (int a = 0; a < 4; a++) for (int b = 0; b < 4; b++) for (int c = 0; c < 2; c++) ep[a][b][c] = 0.f;
        #pragma unroll
        for (int ct = 0; ct < 4; ++ct) {
            const int n = w * 64 + ct * 16 + col;
            const float b1n = sU.r.B1[n];
            const float w20 = sU.r.W2[n * 2], w21 = sU.r.W2[n * 2 + 1];
            #pragma unroll
            for (int rt = 0; rt < 4; ++rt) {
                float z2c = __shfl(acc[rt][ct][0], srcl);
                float h2 = sig(z2c + b1n);
                float d2 = h2 - h2 * h2;
                #pragma unroll
                for (int r = 0; r < 4; ++r) {
                    float gg = ((quad & 1) == 0 && r == 0) ? h2 : d2 * acc[rt][ct][r];
                    ep[rt][r][0] = fmaf(gg, w20, ep[rt][r][0]);
                    ep[rt][r][1] = fmaf(gg, w21, ep[rt][r][1]);
                }
            }
        }
        #pragma unroll
        for (int mask = 1; mask <= 8; mask <<= 1)
            #pragma unroll
            for (int a = 0; a < 4; a++)
                #pragma unroll
                for (int b = 0; b < 4; b++)
                    #pragma unroll
                    for (int c = 0; c < 2; c++)
                        ep[a][b][c] += __shfl_xor(ep[a][b][c], mask);
        __syncthreads();
        if (col == 0) {
            #pragma unroll
            for (int rt = 0; rt < 4; ++rt)
                #pragma unroll
                for (int r = 0; r < 4; ++r) {
                    int row = rt * 16 + quad * 4 + r;
                    dynF[(w * 64 + row) * 2 + 0] = ep[rt][r][0];
                    dynF[(w * 64 + row) * 2 + 1] = ep[rt][r][1];
                }
        }
        __syncthreads();
        if (tid < 128) {
            int row = tid >> 1, j = tid & 1;
            float v = dynF[row * 2 + j] + dynF[(64 + row) * 2 + j]
                    + dynF[(128 + row) * 2 + j] + dynF[(192 + row) * 2 + j];
            if ((row & 7) == 0) v += b2[j];
            dynF[512 + row * 2 + j] = v;
        }
        __syncthreads();
        if (tid < 8) {
            int s = tid;
            size_t M = m0 + s;
            float y0 = dynF[512 + (s * 8) * 2 + 0], y1 = dynF[512 + (s * 8) * 2 + 1];
            float sv = sinf(y0), cv = cosf(y1);
            out[M * 18 + 3 + h] = sv;
            out[M * 18 + 6 + h] = cv;
            out[OUTA + M * 6 + 3 + h] = atan2f(sv, cv);
            float f0 = cosf(y0), f1 = -sinf(y1);
            float inv = 1.0f / fmaf(sv, sv, cv * cv);
            float v0 = 0.f, v1 = 0.f;
            #pragma unroll
            for (int i = 0; i < 7; i++) {
                float r0 = f0 * dynF[512 + (s * 8 + 1 + i) * 2 + 0];
                float r1 = f1 * dynF[512 + (s * 8 + 1 + i) * 2 + 1];
                out[JTOT + M * 63 + (3 + h) * 7 + i] = r0;
                out[JTOT + M * 63 + (6 + h) * 7 + i] = r1;
                out[JANG + M * 42 + (3 + h) * 7 + i] = (cv * r0 - sv * r1) * inv;
                v0 = fmaf(r0, sU.r.Qd[s][i], v0);
                v1 = fmaf(r1, sU.r.Qd[s][i], v1);
            }
            out[M * 18 + 12 + h] = v0;
            out[M * 18 + 15 + h] = v1;
        }
    }
}

extern "C" void kernel_launch(void* const* d_in, const int* in_sizes, int n_in,
                              void* d_out, int out_size, void* d_ws, size_t ws_size,
                              hipStream_t stream) {
    (void)n_in; (void)out_size; (void)ws_size;
    const float* x = (const float*)d_in[0];
    float* out = (float*)d_out;
    unsigned short* ws = (unsigned short*)d_ws;
    const int ns = in_sizes[0] / 14;

    convert_all<<<dim3(1792), 256, 0, stream>>>(
        (const float*)d_in[3], (const float*)d_in[9],
        (const float*)d_in[15], (const float*)d_in[21], ws);

    // groups of 5 blocks: 2 pos tiles (4 samples each) + 3 rpy heads (8 samples)
    fused_mfma<<<dim3((ns / 8) * 5), 256, 32768, stream>>>(
        x,
        (const float*)d_in[1],  (const float*)d_in[2],  (const float*)d_in[4],
        (const float*)d_in[5],  (const float*)d_in[6],
        (const float*)d_in[7],  (const float*)d_in[8],  (const float*)d_in[10],
        (const float*)d_in[11], (const float*)d_in[12],
        (const float*)d_in[13], (const float*)d_in[14], (const float*)d_in[16],
        (const float*)d_in[17], (const float*)d_in[18],
        (const float*)d_in[19], (const float*)d_in[20], (const float*)d_in[22],
        (const float*)d_in[23], (const float*)d_in[24],
        ws, out, ns);
}

// Round 9
// 341.706 us; speedup vs baseline: 1.0230x; 1.0230x over previous
//
#include <hip/hip_runtime.h>
#include <math.h>

typedef __attribute__((ext_vector_type(8))) short short8;
typedef __attribute__((ext_vector_type(4))) float floatx4;

// fast sigmoid: v_mul+v_exp+v_add+v_rcp (no IEEE divide chain; no -ffast-math in harness)
__device__ __forceinline__ float sig(float z) {
    return __builtin_amdgcn_rcpf(1.0f + __expf(-z));
}

__device__ __forceinline__ unsigned short f2bf(float f) {
    unsigned u = __float_as_uint(f);
    u = (u + 0x7FFFu + ((u >> 16) & 1u)) >> 16;
    return (unsigned short)u;
}

// pack two fp32 -> two RNE bf16 in one uint (HW packed cvt when available)
#if __has_builtin(__builtin_amdgcn_cvt_pk_bf16_f32)
typedef __attribute__((ext_vector_type(2))) short short2v;
__device__ __forceinline__ unsigned int pack2bf(float a, float b) {
    short2v r = __builtin_amdgcn_cvt_pk_bf16_f32(a, b);
    return *(unsigned int*)&r;
}
#else
__device__ __forceinline__ unsigned int pack2bf(float a, float b) {
    unsigned ua = __float_as_uint(a), ub = __float_as_uint(b);
    ua += 0x7FFFu + ((ua >> 16) & 1u);
    ub += 0x7FFFu + ((ub >> 16) & 1u);
    return __builtin_amdgcn_perm(ub, ua, 0x07060302);
}
#endif

// All four W1 matrices -> bf16 pre-swizzled MFMA 16x16x32 B-frag order.
// blk = (n>>4)*(H/32) + (k>>5), lane = ((k>>3)&3)*16 + (n&15), j = k&7.
__global__ void convert_all(const float* __restrict__ s0, const float* __restrict__ s1,
                            const float* __restrict__ s2, const float* __restrict__ s3,
                            unsigned short* __restrict__ ws) {
    int idx = blockIdx.x * 256 + threadIdx.x;          // 0 .. 458751
    const float* src; unsigned short* dst; int H, logH, local;
    if (idx < 262144) { src = s0; dst = ws; H = 512; logH = 9; local = idx; }
    else {
        int r = idx - 262144; int m = r >> 16; local = r & 65535;
        H = 256; logH = 8;
        src = (m == 0) ? s1 : (m == 1) ? s2 : s3;
        dst = ws + 262144 + m * 65536;
    }
    int n = local & (H - 1), k = local >> logH;
    int KT = H >> 5;
    int blk = (n >> 4) * KT + (k >> 5);
    int lane = ((k >> 3) & 3) * 16 + (n & 15);
    int j = k & 7;
    dst[(blk * 64 + lane) * 8 + j] = f2bf(src[local]);
}

struct PosS {
    float B0[512], B1[512], W2[1536];
    float Q[8][8], Qd[8][8];
    float Acc[4][64][3], Sum[64][3];
};
struct RpyS {
    float B0[256], B1[256], W2[512];
    float Q[16][8], Qd[16][8];
    float Acc[4][128][2], Sum[128][2];
};

// Fused kernel: 5120 blocks. f%5<2 -> pos tile (8 samples); f%5>=2 -> rpy head (16 samples).
__global__ __launch_bounds__(256, 2)
void fused_mfma(const float* __restrict__ x,
                const float* __restrict__ pW0, const float* __restrict__ pb0,
                const float* __restrict__ pb1,
                const float* __restrict__ pW2, const float* __restrict__ pb2,
                const float* __restrict__ rW0_, const float* __restrict__ rb0_,
                const float* __restrict__ rb1_,
                const float* __restrict__ rW2_, const float* __restrict__ rb2_,
                const float* __restrict__ piW0, const float* __restrict__ pib0,
                const float* __restrict__ pib1,
                const float* __restrict__ piW2, const float* __restrict__ pib2,
                const float* __restrict__ yW0, const float* __restrict__ yb0,
                const float* __restrict__ yb1,
                const float* __restrict__ yW2, const float* __restrict__ yb2,
                const unsigned short* __restrict__ wsBase,
                float* __restrict__ out, int ns)
{
    extern __shared__ unsigned short sA[];      // 64 KB dynamic
    __shared__ union { PosS p; RpyS r; } sU;

    const int tid = threadIdx.x;
    const int f = blockIdx.x;
    const int g = f / 5, r5 = f % 5;
    const size_t JTOT = (size_t)ns * 18, OUTA = (size_t)ns * 81, JANG = (size_t)ns * 87;
    const floatx4 z4 = {0.f, 0.f, 0.f, 0.f};
    const int w = tid >> 6, lane = tid & 63;
    const int quad = lane >> 4, col = lane & 15;
    const int srcl = lane & 47;

    if (r5 < 2) {
        // ================= POS: 7 -> 512 -> 512 -> 3, 8 samples =================
        const int m0 = (g * 2 + r5) * 8;
        const unsigned short* wsW1 = wsBase;

        if (tid < 128) {
            ((float4*)sU.p.B0)[tid] = ((const float4*)pb0)[tid];
            ((float4*)sU.p.B1)[tid] = ((const float4*)pb1)[tid];
        }
        for (int i = tid; i < 384; i += 256) ((float4*)sU.p.W2)[i] = ((const float4*)pW2)[i];
        if (tid < 112) {
            int m = tid / 14, c = tid % 14;
            float v = x[(m0 + m) * 14 + c];
            if (c < 7) sU.p.Q[m][c] = v; else sU.p.Qd[m][c - 7] = v;
        }
        __syncthreads();

        const float4* W04 = (const float4*)pW0;
        #pragma unroll
        for (int t = 0; t < 2; ++t) {
            int item = tid + t * 256;
            int s = item >> 6, k8 = item & 63;
            float q[7], w0v[7][8];
            #pragma unroll
            for (int i = 0; i < 7; i++) {
                q[i] = sU.p.Q[s][i];
                float4 a = W04[i * 128 + k8 * 2], b4 = W04[i * 128 + k8 * 2 + 1];
                w0v[i][0]=a.x; w0v[i][1]=a.y; w0v[i][2]=a.z; w0v[i][3]=a.w;
                w0v[i][4]=b4.x; w0v[i][5]=b4.y; w0v[i][6]=b4.z; w0v[i][7]=b4.w;
            }
            float hv[8], dv[8];
            #pragma unroll
            for (int jj = 0; jj < 8; jj++) {
                float z = sU.p.B0[k8 * 8 + jj];
                #pragma unroll
                for (int i = 0; i < 7; i++) z = fmaf(q[i], w0v[i][jj], z);
                float h = sig(z);
                hv[jj] = h; dv[jj] = h - h * h;
            }
            int kt = k8 >> 2, kq = k8 & 3, sw = kt & 7;
            int rr0 = s * 8;
            {
                uint4 v;
                v.x = pack2bf(hv[0], hv[1]); v.y = pack2bf(hv[2], hv[3]);
                v.z = pack2bf(hv[4], hv[5]); v.w = pack2bf(hv[6], hv[7]);
                *(uint4*)&sA[((rr0 >> 4) * 16 + kt) * 512 + ((kq * 16 + (rr0 & 15)) ^ sw) * 8] = v;
            }
            #pragma unroll
            for (int i = 0; i < 7; i++) {
                int rr = rr0 + 1 + i;
                uint4 v;
                v.x = pack2bf(dv[0] * w0v[i][0], dv[1] * w0v[i][1]);
                v.y = pack2bf(dv[2] * w0v[i][2], dv[3] * w0v[i][3]);
                v.z = pack2bf(dv[4] * w0v[i][4], dv[5] * w0v[i][5]);
                v.w = pack2bf(dv[6] * w0v[i][6], dv[7] * w0v[i][7]);
                *(uint4*)&sA[((rr >> 4) * 16 + kt) * 512 + ((kq * 16 + (rr & 15)) ^ sw) * 8] = v;
            }
        }
        __syncthreads();

        floatx4 acc[4][8];
        #pragma unroll
        for (int rt = 0; rt < 4; rt++)
            #pragma unroll
            for (int ct = 0; ct < 8; ct++) acc[rt][ct] = z4;

        const short8* bbase = (const short8*)wsW1 + (size_t)(w * 8 * 16) * 64 + lane;
        short8 bufA[8], bufB[8];
        #pragma unroll
        for (int ct = 0; ct < 8; ++ct) bufA[ct] = bbase[(ct * 16) * 64];

        for (int kt2 = 0; kt2 < 16; kt2 += 2) {
            #pragma unroll
            for (int ct = 0; ct < 8; ++ct) bufB[ct] = bbase[(ct * 16 + kt2 + 1) * 64];
            {
                const int kt = kt2, sw = kt & 7;
                short8 afr[4];
                #pragma unroll
                for (int rt = 0; rt < 4; ++rt)
                    afr[rt] = *(const short8*)&sA[(rt * 16 + kt) * 512 + (lane ^ sw) * 8];
                #pragma unroll
                for (int ct = 0; ct < 8; ++ct)
                    #pragma unroll
                    for (int rt = 0; rt < 4; ++rt)
                        acc[rt][ct] = __builtin_amdgcn_mfma_f32_16x16x32_bf16(afr[rt], bufA[ct], acc[rt][ct], 0, 0, 0);
            }
            if (kt2 + 2 < 16) {
                #pragma unroll
                for (int ct = 0; ct < 8; ++ct) bufA[ct] = bbase[(ct * 16 + kt2 + 2) * 64];
            }
            {
                const int kt = kt2 + 1, sw = kt & 7;
                short8 afr[4];
                #pragma unroll
                for (int rt = 0; rt < 4; ++rt)
                    afr[rt] = *(const short8*)&sA[(rt * 16 + kt) * 512 + (lane ^ sw) * 8];
                #pragma unroll
                for (int ct = 0; ct < 8; ++ct)
                    #pragma unroll
                    for (int rt = 0; rt < 4; ++rt)
                        acc[rt][ct] = __builtin_amdgcn_mfma_f32_16x16x32_bf16(afr[rt], bufB[ct], acc[rt][ct], 0, 0, 0);
            }
        }

        float ep[4][4][3];
        #pragma unroll
        for (int a = 0; a < 4; a++) for (int b = 0; b < 4; b++) for (int c = 0; c < 3; c++) ep[a][b][c] = 0.f;

        #pragma unroll
        for (int ct = 0; ct < 8; ++ct) {
            const int n = w * 128 + ct * 16 + col;
            const float b1n = sU.p.B1[n];
            const float w20 = sU.p.W2[n * 3], w21 = sU.p.W2[n * 3 + 1], w22 = sU.p.W2[n * 3 + 2];
            #pragma unroll
            for (int rt = 0; rt < 4; ++rt) {
                float z2c = __shfl(acc[rt][ct][0], srcl);
                float h2 = sig(z2c + b1n);
                float d2 = h2 - h2 * h2;
                #pragma unroll
                for (int r = 0; r < 4; ++r) {
                    float gg = ((quad & 1) == 0 && r == 0) ? h2 : d2 * acc[rt][ct][r];
                    ep[rt][r][0] = fmaf(gg, w20, ep[rt][r][0]);
                    ep[rt][r][1] = fmaf(gg, w21, ep[rt][r][1]);
                    ep[rt][r][2] = fmaf(gg, w22, ep[rt][r][2]);
                }
            }
        }

        #pragma unroll
        for (int mask = 1; mask <= 8; mask <<= 1)
            #pragma unroll
            for (int a = 0; a < 4; a++)
                #pragma unroll
                for (int b = 0; b < 4; b++)
                    #pragma unroll
                    for (int c = 0; c < 3; c++)
                        ep[a][b][c] += __shfl_xor(ep[a][b][c], mask);
        if (col == 0) {
            #pragma unroll
            for (int rt = 0; rt < 4; ++rt)
                #pragma unroll
                for (int r = 0; r < 4; ++r) {
                    int row = rt * 16 + quad * 4 + r;
                    sU.p.Acc[w][row][0] = ep[rt][r][0];
                    sU.p.Acc[w][row][1] = ep[rt][r][1];
                    sU.p.Acc[w][row][2] = ep[rt][r][2];
                }
        }
        __syncthreads();

        if (tid < 192) {
            int row = tid / 3, j = tid % 3;
            float v = sU.p.Acc[0][row][j] + sU.p.Acc[1][row][j] + sU.p.Acc[2][row][j] + sU.p.Acc[3][row][j];
            int s = row >> 3, i = row & 7;
            size_t M = m0 + s;
            if (i == 0) { v += pb2[j]; out[M * 18 + j] = v; out[OUTA + M * 6 + j] = v; }
            else        { out[JTOT + M * 63 + j * 7 + (i - 1)] = v;
                          out[JANG + M * 42 + j * 7 + (i - 1)] = v; }
            sU.p.Sum[row][j] = v;
        }
        __syncthreads();
        if (tid < 24) {
            int s = tid / 3, j = tid % 3;
            float vel = 0.f;
            #pragma unroll
            for (int i = 0; i < 7; i++) vel = fmaf(sU.p.Sum[s * 8 + 1 + i][j], sU.p.Qd[s][i], vel);
            out[(size_t)(m0 + s) * 18 + 9 + j] = vel;
        }
    } else {
        // ================= RPY: 7 -> 256 -> 256 -> 2, 16 samples =================
        const int h = r5 - 2;
        const int m0 = g * 16;
        const float* W0 = (h == 0) ? rW0_ : (h == 1) ? piW0 : yW0;
        const float* b0 = (h == 0) ? rb0_ : (h == 1) ? pib0 : yb0;
        const float* b1 = (h == 0) ? rb1_ : (h == 1) ? pib1 : yb1;
        const float* W2 = (h == 0) ? rW2_ : (h == 1) ? piW2 : yW2;
        const float* b2 = (h == 0) ? rb2_ : (h == 1) ? pib2 : yb2;
        const unsigned short* wsW1 = wsBase + 262144 + h * 65536;

        if (tid < 64) {
            ((float4*)sU.r.B0)[tid] = ((const float4*)b0)[tid];
            ((float4*)sU.r.B1)[tid] = ((const float4*)b1)[tid];
        } else if (tid < 192) {
            ((float4*)sU.r.W2)[tid - 64] = ((const float4*)W2)[tid - 64];
        }
        if (tid < 224) {
            int m = tid / 14, c = tid % 14;
            float v = x[(m0 + m) * 14 + c];
            if (c < 7) sU.r.Q[m][c] = v; else sU.r.Qd[m][c - 7] = v;
        }
        __syncthreads();

        const float4* W04 = (const float4*)W0;
        #pragma unroll
        for (int t = 0; t < 2; ++t) {
            int item = tid + t * 256;
            int s = item >> 5, k8 = item & 31;
            float q[7], w0v[7][8];
            #pragma unroll
            for (int i = 0; i < 7; i++) {
                q[i] = sU.r.Q[s][i];
                float4 a = W04[i * 64 + k8 * 2], b4 = W04[i * 64 + k8 * 2 + 1];
                w0v[i][0]=a.x; w0v[i][1]=a.y; w0v[i][2]=a.z; w0v[i][3]=a.w;
                w0v[i][4]=b4.x; w0v[i][5]=b4.y; w0v[i][6]=b4.z; w0v[i][7]=b4.w;
            }
            float hv[8], dv[8];
            #pragma unroll
            for (int jj = 0; jj < 8; jj++) {
                float z = sU.r.B0[k8 * 8 + jj];
                #pragma unroll
                for (int i = 0; i < 7; i++) z = fmaf(q[i], w0v[i][jj], z);
                float hh = sig(z);
                hv[jj] = hh; dv[jj] = hh - hh * hh;
            }
            int kt = k8 >> 2, kq = k8 & 3, sw = kt & 7;
            int rr0 = s * 8;
            {
                uint4 v;
                v.x = pack2bf(hv[0], hv[1]); v.y = pack2bf(hv[2], hv[3]);
                v.z = pack2bf(hv[4], hv[5]); v.w = pack2bf(hv[6], hv[7]);
                *(uint4*)&sA[((rr0 >> 4) * 8 + kt) * 512 + ((kq * 16 + (rr0 & 15)) ^ sw) * 8] = v;
            }
            #pragma unroll
            for (int i = 0; i < 7; i++) {
                int rr = rr0 + 1 + i;
                uint4 v;
                v.x = pack2bf(dv[0] * w0v[i][0], dv[1] * w0v[i][1]);
                v.y = pack2bf(dv[2] * w0v[i][2], dv[3] * w0v[i][3]);
                v.z = pack2bf(dv[4] * w0v[i][4], dv[5] * w0v[i][5]);
                v.w = pack2bf(dv[6] * w0v[i][6], dv[7] * w0v[i][7]);
                *(uint4*)&sA[((rr >> 4) * 8 + kt) * 512 + ((kq * 16 + (rr & 15)) ^ sw) * 8] = v;
            }
        }
        __syncthreads();

        floatx4 acc[8][4];
        #pragma unroll
        for (int rt = 0; rt < 8; rt++)
            #pragma unroll
            for (int ct = 0; ct < 4; ct++) acc[rt][ct] = z4;

        const short8* bbase = (const short8*)wsW1 + (size_t)(w * 4 * 8) * 64 + lane;
        short8 bufA[4], bufB[4];
        #pragma unroll
        for (int ct = 0; ct < 4; ++ct) bufA[ct] = bbase[(ct * 8) * 64];

        for (int kt2 = 0; kt2 < 8; kt2 += 2) {
            #pragma unroll
            for (int ct = 0; ct < 4; ++ct) bufB[ct] = bbase[(ct * 8 + kt2 + 1) * 64];
            {
                const int kt = kt2, sw = kt & 7;
                short8 afr[8];
                #pragma unroll
                for (int rt = 0; rt < 8; ++rt)
                    afr[rt] = *(const short8*)&sA[(rt * 8 + kt) * 512 + (lane ^ sw) * 8];
                #pragma unroll
                for (int ct = 0; ct < 4; ++ct)
                    #pragma unroll
                    for (int rt = 0; rt < 8; ++rt)
                        acc[rt][ct] = __builtin_amdgcn_mfma_f32_16x16x32_bf16(afr[rt], bufA[ct], acc[rt][ct], 0, 0, 0);
            }
            if (kt2 + 2 < 8) {
                #pragma unroll
                for (int ct = 0; ct < 4; ++ct) bufA[ct] = bbase[(ct * 8 + kt2 + 2) * 64];
            }
            {
                const int kt = kt2 + 1, sw = kt & 7;
                short8 afr[8];
                #pragma unroll
                for (int rt = 0; rt < 8; ++rt)
                    afr[rt] = *(const short8*)&sA[(rt * 8 + kt) * 512 + (lane ^ sw) * 8];
                #pragma unroll
                for (int ct = 0; ct < 4; ++ct)
                    #pragma unroll
                    for (int rt = 0; rt < 8; ++rt)
                        acc[rt][ct] = __builtin_amdgcn_mfma_f32_16x16x32_bf16(afr[rt], bufB[ct], acc[rt][ct], 0, 0, 0);
            }
        }

        float ep[8][4][2];
        #pragma unroll
        for (int a = 0; a < 8; a++) for (int b = 0; b < 4; b++) for (int c = 0; c < 2; c++) ep[a][b][c] = 0.f;

        #pragma unroll
        for (int ct = 0; ct < 4; ++ct) {
            const int n = w * 64 + ct * 16 + col;
            const float b1n = sU.r.B1[n];
            const float w20 = sU.r.W2[n * 2], w21 = sU.r.W2[n * 2 + 1];
            #pragma unroll
            for (int rt = 0; rt < 8; ++rt) {
                float z2c = __shfl(acc[rt][ct][0], srcl);
                float h2 = sig(z2c + b1n);
                float d2 = h2 - h2 * h2;
                #pragma unroll
                for (int r = 0; r < 4; ++r) {
                    float gg = ((quad & 1) == 0 && r == 0) ? h2 : d2 * acc[rt][ct][r];
                    ep[rt][r][0] = fmaf(gg, w20, ep[rt][r][0]);
                    ep[rt][r][1] = fmaf(gg, w21, ep[rt][r][1]);
                }
            }
        }

        #pragma unroll
        for (int mask = 1; mask <= 8; mask <<= 1)
            #pragma unroll
            for (int a = 0; a < 8; a++)
                #pragma unroll
                for (int b = 0; b < 4; b++)
                    #pragma unroll
                    for (int c = 0; c < 2; c++)
                        ep[a][b][c] += __shfl_xor(ep[a][b][c], mask);
        if (col == 0) {
            #pragma unroll
            for (int rt = 0; rt < 8; ++rt)
                #pragma unroll
                for (int r = 0; r < 4; ++r) {
                    int row = rt * 16 + quad * 4 + r;
                    sU.r.Acc[w][row][0] = ep[rt][r][0];
                    sU.r.Acc[w][row][1] = ep[rt][r][1];
                }
        }
        __syncthreads();

        if (tid < 256) {
            int row = tid >> 1, j = tid & 1;
            float v = sU.r.Acc[0][row][j] + sU.r.Acc[1][row][j] + sU.r.Acc[2][row][j] + sU.r.Acc[3][row][j];
            if ((row & 7) == 0) v += b2[j];
            sU.r.Sum[row][j] = v;
        }
        __syncthreads();

        if (tid < 16) {
            int s = tid;
            size_t M = m0 + s;
            float y0 = sU.r.Sum[s * 8][0], y1 = sU.r.Sum[s * 8][1];
            float sv = sinf(y0), cv = cosf(y1);
            out[M * 18 + 3 + h] = sv;
            out[M * 18 + 6 + h] = cv;
            out[OUTA + M * 6 + 3 + h] = atan2f(sv, cv);
            float f0 = cosf(y0), f1 = -sinf(y1);
            float inv = __builtin_amdgcn_rcpf(fmaf(sv, sv, cv * cv));
            float v0 = 0.f, v1 = 0.f;
            #pragma unroll
            for (int i = 0; i < 7; i++) {
                float r0 = f0 * sU.r.Sum[s * 8 + 1 + i][0];
                float r1 = f1 * sU.r.Sum[s * 8 + 1 + i][1];
                out[JTOT + M * 63 + (3 + h) * 7 + i] = r0;
                out[JTOT + M * 63 + (6 + h) * 7 + i] = r1;
                out[JANG + M * 42 + (3 + h) * 7 + i] = (cv * r0 - sv * r1) * inv;
                v0 = fmaf(r0, sU.r.Qd[s][i], v0);
                v1 = fmaf(r1, sU.r.Qd[s][i], v1);
            }
            out[M * 18 + 12 + h] = v0;
            out[M * 18 + 15 + h] = v1;
        }
    }
}

extern "C" void kernel_launch(void* const* d_in, const int* in_sizes, int n_in,
                              void* d_out, int out_size, void* d_ws, size_t ws_size,
                              hipStream_t stream) {
    (void)n_in; (void)out_size; (void)ws_size;
    const float* x = (const float*)d_in[0];
    float* out = (float*)d_out;
    unsigned short* ws = (unsigned short*)d_ws;
    const int ns = in_sizes[0] / 14;

    convert_all<<<dim3(1792), 256, 0, stream>>>(
        (const float*)d_in[3], (const float*)d_in[9],
        (const float*)d_in[15], (const float*)d_in[21], ws);

    // 5120 blocks: per group of 5 -> 2 pos tiles (8 samples) + 3 rpy heads (16 samples)
    fused_mfma<<<dim3((ns / 8 / 2) * 5), 256, 65536, stream>>>(
        x,
        (const float*)d_in[1],  (const float*)d_in[2],  (const float*)d_in[4],
        (const float*)d_in[5],  (const float*)d_in[6],
        (const float*)d_in[7],  (const float*)d_in[8],  (const float*)d_in[10],
        (const float*)d_in[11], (const float*)d_in[12],
        (const float*)d_in[13], (const float*)d_in[14], (const float*)d_in[16],
        (const float*)d_in[17], (const float*)d_in[18],
        (const float*)d_in[19], (const float*)d_in[20], (const float*)d_in[22],
        (const float*)d_in[23], (const float*)d_in[24],
        ws, out, ns);
}